// Round 3
// baseline (3435.518 us; speedup 1.0000x reference)
//
#include <hip/hip_runtime.h>
#include <hip/hip_bf16.h>

typedef unsigned short u16;
typedef unsigned int u32;
#define DI __device__ __forceinline__

constexpr int B_ = 8;
constexpr int V_ = 4096;   // 64*64
constexpr int C_ = 256;    // Cin = Cout
constexpr int F_ = 128;
constexpr int E_ = 256;
constexpr int KK_ = 49;    // 7x7

// ---- ws layout (float indices). Total ~11.7 MB. ----
constexpr size_t OFF_XSUM = 0;                      // B*C   = 2048
constexpr size_t OFF_CSUM = OFF_XSUM + 2048;        // B*E   = 2048
constexpr size_t OFF_SPHI = OFF_CSUM + 2048;        // B*F   = 1024
constexpr size_t OFF_A    = OFF_SPHI + 1024;        // B*F   = 1024
constexpr size_t OFF_T    = OFF_A + 1024;           // B*F*E = 262144 (atomic acc, zeroed)
constexpr size_t ZERO_FLOATS = OFF_T + 262144;      // 268288 floats memset to 0
constexpr size_t OFF_RSD  = ZERO_FLOATS;            // B*V = 32768
constexpr size_t OFF_TMP  = OFF_RSD + 32768;        // B*E*C = 524288
constexpr size_t OFF_PHI  = OFF_TMP + 524288;       // bf16 phi: B*V*F u16 (= 2097152 floats worth)

DI float bf2f(u16 u) {
    union { u32 i; float f; } v; v.i = ((u32)u) << 16; return v.f;
}
DI u16 f2bf(float f) {
    union { float f; u32 i; } v; v.f = f;
    u32 r = v.i + 0x7fff + ((v.i >> 16) & 1);   // round-to-nearest-even
    return (u16)(r >> 16);
}

// ---- xsum[b][c] = sum_v x[b,v,c] ----
__global__ void k_xsum(const float* __restrict__ x, float* __restrict__ ws) {
    int b = blockIdx.x >> 3;
    int chunk = blockIdx.x & 7;
    int c = threadIdx.x;
    const float* xb = x + ((size_t)b * V_ + chunk * 512) * C_ + c;
    float s = 0.f;
    for (int v = 0; v < 512; ++v) s += xb[(size_t)v * C_];
    atomicAdd(&ws[OFF_XSUM + b * C_ + c], s);
}

// ---- a[b][f] = mean(x) @ w_a + b_a ----
__global__ void k_a(const float* __restrict__ w_a, const float* __restrict__ b_a,
                    float* __restrict__ ws) {
    int b = blockIdx.x, f = threadIdx.x;
    float acc = b_a[f];
    const float* xs = &ws[OFF_XSUM + b * C_];
    for (int c = 0; c < C_; ++c)
        acc += (xs[c] * (1.0f / 4096.0f)) * w_a[c * F_ + f];
    ws[OFF_A + b * F_ + f] = acc;
}

// ---- phi[b,v,f] = x @ w_phi + b_phi (stored bf16), sphi[b,f] = sum_v phi ----
__global__ void k_phi(const float* __restrict__ x, const float* __restrict__ w_phi,
                      const float* __restrict__ b_phi, float* __restrict__ ws) {
    __shared__ float xsT[C_][8];
    int r0 = blockIdx.x * 8;      // global row (b*V+v)
    int b = r0 >> 12;
    int tid = threadIdx.x;
    const float* xb = x + (size_t)r0 * C_;
    for (int i = tid; i < 8 * C_; i += 128) xsT[i & 255][i >> 8] = xb[i];
    __syncthreads();
    int f = tid;
    float bp = b_phi[f];
    float acc[8];
#pragma unroll
    for (int r = 0; r < 8; ++r) acc[r] = bp;
    const float* wp = w_phi + f;
    for (int c = 0; c < C_; ++c) {
        float w = wp[c * F_];
        float4 xa = *(const float4*)&xsT[c][0];
        float4 xb4 = *(const float4*)&xsT[c][4];
        acc[0] += xa.x * w;  acc[1] += xa.y * w;  acc[2] += xa.z * w;  acc[3] += xa.w * w;
        acc[4] += xb4.x * w; acc[5] += xb4.y * w; acc[6] += xb4.z * w; acc[7] += xb4.w * w;
    }
    u16* phiw = (u16*)&ws[OFF_PHI];
    float ssum = 0.f;
#pragma unroll
    for (int r = 0; r < 8; ++r) {
        phiw[(size_t)(r0 + r) * F_ + f] = f2bf(acc[r]);
        ssum += acc[r];
    }
    atomicAdd(&ws[OFF_SPHI + b * F_ + f], ssum);
}

// ---- fused: G_tile = phi^T @ x_shift (16f x 256c), then t += G_tile @ w_m[kk] ----
__global__ void k_g(const float* __restrict__ x, const float* __restrict__ w_m,
                    float* __restrict__ ws) {
    __shared__ float Gs[16][256];   // 16 KB
    int blk = blockIdx.x;
    int b = blk / (KK_ * 8);
    int rem = blk % (KK_ * 8);
    int kk = rem >> 3;
    int f0 = (rem & 7) * 16;
    int dy = kk / 7 - 3, dx = kk % 7 - 3;
    int h0 = max(0, -dy), h1 = min(64, 64 - dy);
    int w0 = max(0, -dx), w1 = min(64, 64 - dx);
    int tid = threadIdx.x;
    int c0 = tid * 4;
    float acc[16][4];
#pragma unroll
    for (int j = 0; j < 16; ++j)
#pragma unroll
        for (int q = 0; q < 4; ++q) acc[j][q] = 0.f;

    const float* xb = x + (size_t)b * V_ * C_ + c0;
    const u16* phb = (const u16*)&ws[OFF_PHI] + (size_t)b * V_ * F_ + f0;
    for (int h = h0; h < h1; ++h) {
        const float* xrow = xb + (size_t)((h + dy) * 64 + dx) * C_;
        const u16* prow = phb + (size_t)(h * 64) * F_;
        for (int w = w0; w < w1; ++w) {
            float4 xu = *(const float4*)(xrow + (size_t)w * C_);
            const u16* pr = prow + (size_t)w * F_;
            uint4 pa = *(const uint4*)(pr);
            uint4 pb = *(const uint4*)(pr + 8);
            float p[16];
            p[0] = bf2f(pa.x & 0xffff); p[1] = bf2f(pa.x >> 16);
            p[2] = bf2f(pa.y & 0xffff); p[3] = bf2f(pa.y >> 16);
            p[4] = bf2f(pa.z & 0xffff); p[5] = bf2f(pa.z >> 16);
            p[6] = bf2f(pa.w & 0xffff); p[7] = bf2f(pa.w >> 16);
            p[8] = bf2f(pb.x & 0xffff); p[9] = bf2f(pb.x >> 16);
            p[10] = bf2f(pb.y & 0xffff); p[11] = bf2f(pb.y >> 16);
            p[12] = bf2f(pb.z & 0xffff); p[13] = bf2f(pb.z >> 16);
            p[14] = bf2f(pb.w & 0xffff); p[15] = bf2f(pb.w >> 16);
#pragma unroll
            for (int j = 0; j < 16; ++j) {
                acc[j][0] += p[j] * xu.x; acc[j][1] += p[j] * xu.y;
                acc[j][2] += p[j] * xu.z; acc[j][3] += p[j] * xu.w;
            }
        }
    }
#pragma unroll
    for (int j = 0; j < 16; ++j)
        *(float4*)&Gs[j][c0] = make_float4(acc[j][0], acc[j][1], acc[j][2], acc[j][3]);
    __syncthreads();

    // phase 2: t[b, f0+j, e] += sum_c Gs[j][c] * w_m[kk, c, e]
    int lane = tid;   // 64 lanes cover e0+lane
    const float* wmk = w_m + (size_t)kk * C_ * E_;
    for (int e0 = 0; e0 < E_; e0 += 64) {
        float tl[16];
#pragma unroll
        for (int j = 0; j < 16; ++j) tl[j] = 0.f;
        for (int c = 0; c < C_; c += 4) {
            float wv0 = wmk[(size_t)(c + 0) * E_ + e0 + lane];
            float wv1 = wmk[(size_t)(c + 1) * E_ + e0 + lane];
            float wv2 = wmk[(size_t)(c + 2) * E_ + e0 + lane];
            float wv3 = wmk[(size_t)(c + 3) * E_ + e0 + lane];
#pragma unroll
            for (int j = 0; j < 16; ++j) {
                float4 g = *(const float4*)&Gs[j][c];
                tl[j] += g.x * wv0 + g.y * wv1 + g.z * wv2 + g.w * wv3;
            }
        }
#pragma unroll
        for (int j = 0; j < 16; ++j)
            atomicAdd(&ws[OFF_T + ((size_t)(b * F_ + f0 + j)) * E_ + e0 + lane], tl[j]);
    }
}

// ---- t = a[b,f] * (t + sphi[b,f]*b_m[e]) ----
__global__ void k_tfix(const float* __restrict__ b_m, float* __restrict__ ws) {
    int blk = blockIdx.x;
    int b = blk >> 7, f = blk & 127, e = threadIdx.x;
    float av = ws[OFF_A + b * F_ + f];
    float sp = ws[OFF_SPHI + b * F_ + f];
    size_t idx = OFF_T + ((size_t)(b * F_ + f)) * E_ + e;
    ws[idx] = av * (ws[idx] + sp * b_m[e]);
}

// ---- Hmat = |phi @ t| (f32 -> hm in d_out), rsD, csum ----
__global__ void k_hd(float* __restrict__ ws, float* __restrict__ hm) {
    __shared__ float phT[F_][4];
    __shared__ float red[4][4];
    int gv0 = blockIdx.x * 4;
    int b = gv0 >> 12;
    int tid = threadIdx.x;
    const u16* phb = (const u16*)&ws[OFF_PHI] + (size_t)gv0 * F_;
    for (int i = tid; i < 4 * F_; i += 256) phT[i & 127][i >> 7] = bf2f(phb[i]);
    __syncthreads();
    int e = tid;
    const float* tb = &ws[OFF_T + (size_t)b * F_ * E_ + e];
    float h[4] = {0.f, 0.f, 0.f, 0.f};
    for (int f = 0; f < F_; ++f) {
        float tv = tb[(size_t)f * E_];
        float4 pp = *(const float4*)&phT[f][0];
        h[0] += pp.x * tv; h[1] += pp.y * tv; h[2] += pp.z * tv; h[3] += pp.w * tv;
    }
#pragma unroll
    for (int p = 0; p < 4; ++p) h[p] = fabsf(h[p]);
    float* hrow = hm + (size_t)gv0 * E_ + e;
#pragma unroll
    for (int p = 0; p < 4; ++p) hrow[(size_t)p * E_] = h[p];
    atomicAdd(&ws[OFF_CSUM + b * E_ + e], h[0] + h[1] + h[2] + h[3]);
#pragma unroll
    for (int off = 32; off > 0; off >>= 1) {
#pragma unroll
        for (int p = 0; p < 4; ++p) h[p] += __shfl_down(h[p], off, 64);
    }
    int lane = tid & 63, wid = tid >> 6;
    if (lane == 0) {
#pragma unroll
        for (int p = 0; p < 4; ++p) red[wid][p] = h[p];
    }
    __syncthreads();
    if (tid < 4) {
        float d = red[0][tid] + red[1][tid] + red[2][tid] + red[3][tid];
        ws[OFF_RSD + gv0 + tid] = rsqrtf(d);
    }
}

// ---- tmp[b,e,c] = (1/csum[b,e]) * sum_v hm[b,v,e]*rsD[b,v]*x[b,v,c] ----
__global__ void k_tmp(const float* __restrict__ x, float* __restrict__ ws,
                      const float* __restrict__ hm) {
    int b = blockIdx.x >> 5;
    int e0 = (blockIdx.x & 31) * 8;
    int c = threadIdx.x;
    float acc[8] = {0.f, 0.f, 0.f, 0.f, 0.f, 0.f, 0.f, 0.f};
    const float* hb = hm + (size_t)b * V_ * E_ + e0;
    const float* xb = x + (size_t)b * V_ * C_ + c;
    const float* rb = &ws[OFF_RSD + b * V_];
    for (int v = 0; v < V_; ++v) {
        float xr = xb[(size_t)v * C_] * rb[v];
        float4 hA = *(const float4*)(hb + (size_t)v * E_);
        float4 hB = *(const float4*)(hb + (size_t)v * E_ + 4);
        acc[0] += hA.x * xr; acc[1] += hA.y * xr; acc[2] += hA.z * xr; acc[3] += hA.w * xr;
        acc[4] += hB.x * xr; acc[5] += hB.y * xr; acc[6] += hB.z * xr; acc[7] += hB.w * xr;
    }
#pragma unroll
    for (int j = 0; j < 8; ++j) {
        float binv = 1.0f / ws[OFF_CSUM + b * E_ + e0 + j];
        ws[OFF_TMP + ((size_t)b * E_ + e0 + j) * C_ + c] = acc[j] * binv;
    }
}

// ---- out = (x - rsD * (hm @ tmp)) @ W2 + b2 ; overwrites hm (d_out) in place ----
__global__ void k_out(const float* __restrict__ x, const float* __restrict__ w2,
                      const float* __restrict__ b2, const float* __restrict__ ws,
                      float* __restrict__ io) {
    __shared__ float hsT[E_][8];
    __shared__ float dT[C_][8];
    __shared__ float rsd_s[8];
    int gv0 = blockIdx.x * 8;
    int b = gv0 >> 12;
    int tid = threadIdx.x;
    const float* hmr = io + (size_t)gv0 * E_;
#pragma unroll
    for (int p = 0; p < 8; ++p) hsT[tid][p] = hmr[(size_t)p * E_ + tid];
    if (tid < 8) rsd_s[tid] = ws[OFF_RSD + gv0 + tid];
    __syncthreads();
    int c = tid;
    float agg[8] = {0.f, 0.f, 0.f, 0.f, 0.f, 0.f, 0.f, 0.f};
    const float* tb = &ws[OFF_TMP + (size_t)b * E_ * C_ + c];
    for (int e = 0; e < E_; ++e) {
        float tv = tb[(size_t)e * C_];
        float4 hA = *(const float4*)&hsT[e][0];
        float4 hB = *(const float4*)&hsT[e][4];
        agg[0] += hA.x * tv; agg[1] += hA.y * tv; agg[2] += hA.z * tv; agg[3] += hA.w * tv;
        agg[4] += hB.x * tv; agg[5] += hB.y * tv; agg[6] += hB.z * tv; agg[7] += hB.w * tv;
    }
    const float* xb = x + (size_t)gv0 * C_ + c;
#pragma unroll
    for (int p = 0; p < 8; ++p) dT[c][p] = xb[(size_t)p * C_] - rsd_s[p] * agg[p];
    __syncthreads();
    float o[8] = {0.f, 0.f, 0.f, 0.f, 0.f, 0.f, 0.f, 0.f};
    const float* wp = w2 + c;
    for (int cc = 0; cc < C_; ++cc) {
        float wv = wp[(size_t)cc * C_];
        float4 dA = *(const float4*)&dT[cc][0];
        float4 dB = *(const float4*)&dT[cc][4];
        o[0] += dA.x * wv; o[1] += dA.y * wv; o[2] += dA.z * wv; o[3] += dA.w * wv;
        o[4] += dB.x * wv; o[5] += dB.y * wv; o[6] += dB.z * wv; o[7] += dB.w * wv;
    }
    float bias = b2[c];
    __syncthreads();
    float* ob = io + (size_t)gv0 * C_ + c;
#pragma unroll
    for (int p = 0; p < 8; ++p) ob[(size_t)p * C_] = o[p] + bias;
}

extern "C" void kernel_launch(void* const* d_in, const int* in_sizes, int n_in,
                              void* d_out, int out_size, void* d_ws, size_t ws_size,
                              hipStream_t stream) {
    const float* x     = (const float*)d_in[0];
    const float* w_phi = (const float*)d_in[1];
    const float* b_phi = (const float*)d_in[2];
    const float* w_a   = (const float*)d_in[3];
    const float* b_a   = (const float*)d_in[4];
    const float* w_m   = (const float*)d_in[5];
    const float* b_m   = (const float*)d_in[6];
    const float* w2    = (const float*)d_in[7];
    const float* b2    = (const float*)d_in[8];
    float* ws = (float*)d_ws;
    float* io = (float*)d_out;   // doubles as Hmat scratch then final output

    hipMemsetAsync(ws, 0, ZERO_FLOATS * sizeof(float), stream);
    k_xsum<<<dim3(64), dim3(256), 0, stream>>>(x, ws);
    k_a<<<dim3(8), dim3(128), 0, stream>>>(w_a, b_a, ws);
    k_phi<<<dim3(4096), dim3(128), 0, stream>>>(x, w_phi, b_phi, ws);
    k_g<<<dim3(3136), dim3(64), 0, stream>>>(x, w_m, ws);
    k_tfix<<<dim3(1024), dim3(256), 0, stream>>>(b_m, ws);
    k_hd<<<dim3(8192), dim3(256), 0, stream>>>(ws, io);
    k_tmp<<<dim3(256), dim3(256), 0, stream>>>(x, ws, io);
    k_out<<<dim3(4096), dim3(256), 0, stream>>>(x, w2, b2, ws, io);
}

// Round 4
// 1379.406 us; speedup vs baseline: 2.4906x; 2.4906x over previous
//
#include <hip/hip_runtime.h>
#include <hip/hip_bf16.h>

typedef unsigned short u16;
typedef unsigned int u32;
#define DI __device__ __forceinline__

typedef __attribute__((ext_vector_type(8))) short v8s;
typedef __attribute__((ext_vector_type(4))) float v4f;

constexpr int B_ = 8;
constexpr int V_ = 4096;   // 64*64
constexpr int C_ = 256;    // Cin = Cout
constexpr int F_ = 128;
constexpr int E_ = 256;
constexpr int KK_ = 49;    // 7x7
constexpr int PW = 70;     // padded width (64 + 2*3)
constexpr int PA = 4900;   // 70*70

// ---- ws layout (float indices) ----
constexpr size_t OFF_XSUM = 0;                      // 2048
constexpr size_t OFF_CSUM = 2048;                   // 2048
constexpr size_t OFF_SPHI = 4096;                   // 1024
constexpr size_t OFF_A    = 5120;                   // 1024
constexpr size_t ZERO_SMALL = 5120;                 // memset region (atomic accumulators)
constexpr size_t OFF_T    = 6144;                   // B*F*E = 262144
constexpr size_t ZERO_OLD = OFF_T + 262144;         // 268288 (fallback path zeroes this much)
constexpr size_t OFF_RSD  = 268288;                 // B*V = 32768
constexpr size_t OFF_TMP  = 301056;                 // B*E*C = 524288
constexpr size_t OFF_PHI  = 825344;                 // bf16 phi[v][f]: B*V*F u16 = 2097152 floats
constexpr size_t OFF_PHIT = 2922496;                // bf16 phiT[f][v]: 2097152 floats
constexpr size_t OFF_XPT  = 5019648;                // bf16 xpadT[b][c][4900]: 5017600 + 16 slack
constexpr size_t XPT_FLOATS = 5017616;
constexpr size_t OFF_WMT  = OFF_XPT + XPT_FLOATS;   // 10037264: bf16 wmT[kk][e][c]: 1605632 floats
constexpr size_t WS_TOTAL_FLOATS = OFF_WMT + 1605632; // 11642896 -> 46.6 MB
constexpr size_t WS_NEED_BYTES = WS_TOTAL_FLOATS * 4;
constexpr size_t WS_OLD_BYTES = (OFF_PHI + 2097152) * 4;  // 11.7 MB fallback

DI float bf2f(u16 u) {
    union { u32 i; float f; } v; v.i = ((u32)u) << 16; return v.f;
}
DI u16 f2bf(float f) {
    union { float f; u32 i; } v; v.f = f;
    u32 r = v.i + 0x7fff + ((v.i >> 16) & 1);
    return (u16)(r >> 16);
}

// ---- xsum[b][c] = sum_v x[b,v,c] ----
__global__ void k_xsum(const float* __restrict__ x, float* __restrict__ ws) {
    int b = blockIdx.x >> 3;
    int chunk = blockIdx.x & 7;
    int c = threadIdx.x;
    const float* xb = x + ((size_t)b * V_ + chunk * 512) * C_ + c;
    float s = 0.f;
    for (int v = 0; v < 512; ++v) s += xb[(size_t)v * C_];
    atomicAdd(&ws[OFF_XSUM + b * C_ + c], s);
}

// ---- a[b][f] = mean(x) @ w_a + b_a ----
__global__ void k_a(const float* __restrict__ w_a, const float* __restrict__ b_a,
                    float* __restrict__ ws) {
    int b = blockIdx.x, f = threadIdx.x;
    float acc = b_a[f];
    const float* xs = &ws[OFF_XSUM + b * C_];
    for (int c = 0; c < C_; ++c)
        acc += (xs[c] * (1.0f / 4096.0f)) * w_a[c * F_ + f];
    ws[OFF_A + b * F_ + f] = acc;
}

// ---- phi = x @ w_phi + b_phi (bf16), sphi; optionally also phiT[f][v] ----
__global__ void k_phi(const float* __restrict__ x, const float* __restrict__ w_phi,
                      const float* __restrict__ b_phi, float* __restrict__ ws,
                      int writePhiT) {
    __shared__ float xsT[C_][8];
    int r0 = blockIdx.x * 8;
    int b = r0 >> 12;
    int v0 = r0 & 4095;
    int tid = threadIdx.x;
    const float* xb = x + (size_t)r0 * C_;
    for (int i = tid; i < 8 * C_; i += 128) xsT[i & 255][i >> 8] = xb[i];
    __syncthreads();
    int f = tid;
    float bp = b_phi[f];
    float acc[8];
#pragma unroll
    for (int r = 0; r < 8; ++r) acc[r] = bp;
    const float* wp = w_phi + f;
    for (int c = 0; c < C_; ++c) {
        float w = wp[c * F_];
        float4 xa = *(const float4*)&xsT[c][0];
        float4 xb4 = *(const float4*)&xsT[c][4];
        acc[0] += xa.x * w;  acc[1] += xa.y * w;  acc[2] += xa.z * w;  acc[3] += xa.w * w;
        acc[4] += xb4.x * w; acc[5] += xb4.y * w; acc[6] += xb4.z * w; acc[7] += xb4.w * w;
    }
    u16* phiw = (u16*)&ws[OFF_PHI];
    u16 pb[8];
    float ssum = 0.f;
#pragma unroll
    for (int r = 0; r < 8; ++r) {
        pb[r] = f2bf(acc[r]);
        phiw[(size_t)(r0 + r) * F_ + f] = pb[r];
        ssum += acc[r];
    }
    if (writePhiT) {
        u16* phiT = (u16*)&ws[OFF_PHIT];
        uint4 q;
        q.x = (u32)pb[0] | ((u32)pb[1] << 16);
        q.y = (u32)pb[2] | ((u32)pb[3] << 16);
        q.z = (u32)pb[4] | ((u32)pb[5] << 16);
        q.w = (u32)pb[6] | ((u32)pb[7] << 16);
        *(uint4*)(phiT + ((size_t)(b * F_ + f)) * V_ + v0) = q;
    }
    atomicAdd(&ws[OFF_SPHI + b * F_ + f], ssum);
}

// ---- xpadT[b][c][(h+3)*70 + (w+3)] = bf16(x[b,h,w,c]), halo pre-zeroed ----
__global__ void k_padx(const float* __restrict__ x, float* __restrict__ ws) {
    __shared__ float tile[64][68];
    int b = blockIdx.x >> 6;
    int h = blockIdx.x & 63;
    int tid = threadIdx.x;
    u16* xpt = (u16*)&ws[OFF_XPT];
    for (int cc = 0; cc < 4; ++cc) {
        int c0 = cc * 64;
        int w = tid >> 2, q = tid & 3;
        const float* xr = x + ((size_t)(b * V_ + h * 64 + w)) * C_ + c0 + q * 16;
        float4 f0 = *(const float4*)(xr);
        float4 f1 = *(const float4*)(xr + 4);
        float4 f2 = *(const float4*)(xr + 8);
        float4 f3 = *(const float4*)(xr + 12);
        __syncthreads();
        *(float4*)&tile[w][q * 16]      = f0;
        *(float4*)&tile[w][q * 16 + 4]  = f1;
        *(float4*)&tile[w][q * 16 + 8]  = f2;
        *(float4*)&tile[w][q * 16 + 12] = f3;
        __syncthreads();
        int c = tid >> 2, j4 = tid & 3;
        u16* dst = xpt + ((size_t)(b * C_ + c0 + c)) * PA + (h + 3) * PW + 3 + j4 * 16;
#pragma unroll
        for (int ww = 0; ww < 16; ++ww) dst[ww] = f2bf(tile[j4 * 16 + ww][c]);
    }
}

// ---- wmT[kk][e][c] = bf16(w_m[kk][c][e]) ----
__global__ void k_wmt(const float* __restrict__ w_m, float* __restrict__ ws) {
    int kk = blockIdx.x;
    int e = threadIdx.x;
    u16* wmt = (u16*)&ws[OFF_WMT];
    for (int c0 = 0; c0 < C_; c0 += 8) {
        u16 pk[8];
#pragma unroll
        for (int i = 0; i < 8; ++i)
            pk[i] = f2bf(w_m[((size_t)kk * C_ + c0 + i) * E_ + e]);
        uint4 q;
        q.x = (u32)pk[0] | ((u32)pk[1] << 16);
        q.y = (u32)pk[2] | ((u32)pk[3] << 16);
        q.z = (u32)pk[4] | ((u32)pk[5] << 16);
        q.w = (u32)pk[6] | ((u32)pk[7] << 16);
        *(uint4*)(wmt + ((size_t)(kk * E_ + e)) * C_ + c0) = q;
    }
}

// ---- MFMA: G[b,kk][f][c] = sum_v phi[v,f] * xpad[v+off,c]  (bf16 out) ----
__global__ __launch_bounds__(512, 1) void k_gemm1(const float* __restrict__ ws_c,
                                                  u16* __restrict__ G) {
    const float* ws = ws_c;
    __shared__ u16 lds_a[F_ * 32];   // 8 KB  [f][v]
    __shared__ u16 lds_b[C_ * 32];   // 16 KB [c][v]
    int b = blockIdx.x / KK_;
    int kk = blockIdx.x % KK_;
    int ky = kk / 7, kx = kk % 7;
    int tid = threadIdx.x;
    int wave = tid >> 6, lane = tid & 63, quad = lane >> 4, l15 = lane & 15;
    int mi2 = wave >> 2;      // f-half (0/1)
    int ni2 = wave & 3;       // c-quarter (0..3)
    int fA = tid >> 2, vsA = (tid & 3) * 8;       // A staging role
    int cB = tid >> 1, sB = (tid & 1) * 16;       // B staging role

    const u16* phiT = (const u16*)&ws[OFF_PHIT] + (size_t)b * F_ * V_;
    const u16* xpt  = (const u16*)&ws[OFF_XPT] + (size_t)b * C_ * PA;

    v4f acc[4][4];
#pragma unroll
    for (int i = 0; i < 4; ++i)
#pragma unroll
        for (int j = 0; j < 4; ++j) acc[i][j] = (v4f){0.f, 0.f, 0.f, 0.f};

    for (int chunk = 0; chunk < 128; ++chunk) {
        int v0 = chunk * 32;
        int h = v0 >> 6, w0 = v0 & 63;
        // global loads (prefetch into regs)
        uint4 a4 = *(const uint4*)(phiT + (size_t)fA * V_ + v0 + vsA);
        size_t idx0 = (size_t)cB * PA + (size_t)((h + ky) * PW + w0 + kx + sB);
        int r8 = (int)(idx0 & 7);
        const u16* basep = xpt + (idx0 - r8);
        uint4 b0 = *(const uint4*)(basep);
        uint4 b1 = *(const uint4*)(basep + 8);
        uint4 b2 = *(const uint4*)(basep + 16);
        u32 w[12] = {b0.x, b0.y, b0.z, b0.w, b1.x, b1.y, b1.z, b1.w,
                     b2.x, b2.y, b2.z, b2.w};
        u32 o[8];
        int j0 = r8 >> 1;
        if (r8 & 1) {
#pragma unroll
            for (int i = 0; i < 8; ++i) o[i] = (w[j0 + i] >> 16) | (w[j0 + i + 1] << 16);
        } else {
#pragma unroll
            for (int i = 0; i < 8; ++i) o[i] = w[j0 + i];
        }
        __syncthreads();
        *(uint4*)&lds_a[fA * 32 + vsA] = a4;
        *(uint4*)&lds_b[cB * 32 + sB]     = (uint4){o[0], o[1], o[2], o[3]};
        *(uint4*)&lds_b[cB * 32 + sB + 8] = (uint4){o[4], o[5], o[6], o[7]};
        __syncthreads();
        v8s afr[4], bfr[4];
#pragma unroll
        for (int ai = 0; ai < 4; ++ai)
            afr[ai] = *(const v8s*)&lds_a[(mi2 * 64 + ai * 16 + l15) * 32 + quad * 8];
#pragma unroll
        for (int bi = 0; bi < 4; ++bi)
            bfr[bi] = *(const v8s*)&lds_b[(ni2 * 64 + bi * 16 + l15) * 32 + quad * 8];
#pragma unroll
        for (int ai = 0; ai < 4; ++ai)
#pragma unroll
            for (int bi = 0; bi < 4; ++bi)
                acc[ai][bi] = __builtin_amdgcn_mfma_f32_16x16x32_bf16(
                    afr[ai], bfr[bi], acc[ai][bi], 0, 0, 0);
    }
    // epilogue: store G bf16, D-layout: m = quad*4+r, n = l15
    u16* Gb = G + ((size_t)(b * KK_ + kk)) * F_ * C_;
#pragma unroll
    for (int ai = 0; ai < 4; ++ai) {
#pragma unroll
        for (int bi = 0; bi < 4; ++bi) {
            int c = ni2 * 64 + bi * 16 + l15;
#pragma unroll
            for (int r = 0; r < 4; ++r) {
                int f = mi2 * 64 + ai * 16 + quad * 4 + r;
                Gb[(size_t)f * C_ + c] = f2bf(acc[ai][bi][r]);
            }
        }
    }
}

// ---- MFMA: t[b][f][e] = sum_{kk,c} G[b,kk][f][c] * wmT[kk][e][c] ----
__global__ void k_gemm2(const u16* __restrict__ G, float* __restrict__ ws) {
    int b = blockIdx.x >> 3;
    int fi = (blockIdx.x >> 2) & 1;
    int ei = blockIdx.x & 3;
    int tid = threadIdx.x;
    int wave = tid >> 6, lane = tid & 63, quad = lane >> 4, l15 = lane & 15;
    int fbase = fi * 64 + wave * 16;
    int ebase = ei * 64;
    const u16* wmt = (const u16*)&ws[OFF_WMT];
    const u16* Gb = G + (size_t)b * KK_ * F_ * C_;
    v4f acc[4];
#pragma unroll
    for (int i = 0; i < 4; ++i) acc[i] = (v4f){0.f, 0.f, 0.f, 0.f};
    for (int kk = 0; kk < KK_; ++kk) {
        const u16* Ga = Gb + ((size_t)kk * F_ + fbase + l15) * C_;
        const u16* Wb = wmt + ((size_t)kk * E_ + ebase + l15) * C_;
#pragma unroll 2
        for (int cs = 0; cs < 8; ++cs) {
            v8s af = *(const v8s*)(Ga + cs * 32 + quad * 8);
#pragma unroll
            for (int nt = 0; nt < 4; ++nt) {
                v8s bf = *(const v8s*)(Wb + (size_t)nt * 16 * C_ + cs * 32 + quad * 8);
                acc[nt] = __builtin_amdgcn_mfma_f32_16x16x32_bf16(af, bf, acc[nt], 0, 0, 0);
            }
        }
    }
#pragma unroll
    for (int nt = 0; nt < 4; ++nt)
#pragma unroll
        for (int r = 0; r < 4; ++r)
            ws[OFF_T + ((size_t)(b * F_ + fbase + quad * 4 + r)) * E_ + ebase + nt * 16 + l15] =
                acc[nt][r];
}

// ---- OLD fallback conv kernel (atomic version, reads phi bf16) ----
__global__ void k_g_old(const float* __restrict__ x, const float* __restrict__ w_m,
                        float* __restrict__ ws) {
    __shared__ float Gs[16][256];
    int blk = blockIdx.x;
    int b = blk / (KK_ * 8);
    int rem = blk % (KK_ * 8);
    int kk = rem >> 3;
    int f0 = (rem & 7) * 16;
    int dy = kk / 7 - 3, dx = kk % 7 - 3;
    int h0 = max(0, -dy), h1 = min(64, 64 - dy);
    int w0 = max(0, -dx), w1 = min(64, 64 - dx);
    int tid = threadIdx.x;
    int c0 = tid * 4;
    float acc[16][4];
#pragma unroll
    for (int j = 0; j < 16; ++j)
#pragma unroll
        for (int q = 0; q < 4; ++q) acc[j][q] = 0.f;
    const float* xb = x + (size_t)b * V_ * C_ + c0;
    const u16* phb = (const u16*)&ws[OFF_PHI] + (size_t)b * V_ * F_ + f0;
    for (int h = h0; h < h1; ++h) {
        const float* xrow = xb + (size_t)((h + dy) * 64 + dx) * C_;
        const u16* prow = phb + (size_t)(h * 64) * F_;
        for (int w = w0; w < w1; ++w) {
            float4 xu = *(const float4*)(xrow + (size_t)w * C_);
            const u16* pr = prow + (size_t)w * F_;
            uint4 pa = *(const uint4*)(pr);
            uint4 pb = *(const uint4*)(pr + 8);
            float p[16];
            p[0] = bf2f(pa.x & 0xffff); p[1] = bf2f(pa.x >> 16);
            p[2] = bf2f(pa.y & 0xffff); p[3] = bf2f(pa.y >> 16);
            p[4] = bf2f(pa.z & 0xffff); p[5] = bf2f(pa.z >> 16);
            p[6] = bf2f(pa.w & 0xffff); p[7] = bf2f(pa.w >> 16);
            p[8] = bf2f(pb.x & 0xffff); p[9] = bf2f(pb.x >> 16);
            p[10] = bf2f(pb.y & 0xffff); p[11] = bf2f(pb.y >> 16);
            p[12] = bf2f(pb.z & 0xffff); p[13] = bf2f(pb.z >> 16);
            p[14] = bf2f(pb.w & 0xffff); p[15] = bf2f(pb.w >> 16);
#pragma unroll
            for (int j = 0; j < 16; ++j) {
                acc[j][0] += p[j] * xu.x; acc[j][1] += p[j] * xu.y;
                acc[j][2] += p[j] * xu.z; acc[j][3] += p[j] * xu.w;
            }
        }
    }
#pragma unroll
    for (int j = 0; j < 16; ++j)
        *(float4*)&Gs[j][c0] = make_float4(acc[j][0], acc[j][1], acc[j][2], acc[j][3]);
    __syncthreads();
    int lane = tid;
    const float* wmk = w_m + (size_t)kk * C_ * E_;
    for (int e0 = 0; e0 < E_; e0 += 64) {
        float tl[16];
#pragma unroll
        for (int j = 0; j < 16; ++j) tl[j] = 0.f;
        for (int c = 0; c < C_; c += 4) {
            float wv0 = wmk[(size_t)(c + 0) * E_ + e0 + lane];
            float wv1 = wmk[(size_t)(c + 1) * E_ + e0 + lane];
            float wv2 = wmk[(size_t)(c + 2) * E_ + e0 + lane];
            float wv3 = wmk[(size_t)(c + 3) * E_ + e0 + lane];
#pragma unroll
            for (int j = 0; j < 16; ++j) {
                float4 g = *(const float4*)&Gs[j][c];
                tl[j] += g.x * wv0 + g.y * wv1 + g.z * wv2 + g.w * wv3;
            }
        }
#pragma unroll
        for (int j = 0; j < 16; ++j)
            atomicAdd(&ws[OFF_T + ((size_t)(b * F_ + f0 + j)) * E_ + e0 + lane], tl[j]);
    }
}

// ---- t = a[b,f] * (t + sphi[b,f]*b_m[e]) ----
__global__ void k_tfix(const float* __restrict__ b_m, float* __restrict__ ws) {
    int blk = blockIdx.x;
    int b = blk >> 7, f = blk & 127, e = threadIdx.x;
    float av = ws[OFF_A + b * F_ + f];
    float sp = ws[OFF_SPHI + b * F_ + f];
    size_t idx = OFF_T + ((size_t)(b * F_ + f)) * E_ + e;
    ws[idx] = av * (ws[idx] + sp * b_m[e]);
}

// ---- Hmat = |phi @ t| (f32 -> hm in d_out), rsD, csum ----
__global__ void k_hd(float* __restrict__ ws, float* __restrict__ hm) {
    __shared__ float phT[F_][4];
    __shared__ float red[4][4];
    int gv0 = blockIdx.x * 4;
    int b = gv0 >> 12;
    int tid = threadIdx.x;
    const u16* phb = (const u16*)&ws[OFF_PHI] + (size_t)gv0 * F_;
    for (int i = tid; i < 4 * F_; i += 256) phT[i & 127][i >> 7] = bf2f(phb[i]);
    __syncthreads();
    int e = tid;
    const float* tb = &ws[OFF_T + (size_t)b * F_ * E_ + e];
    float h[4] = {0.f, 0.f, 0.f, 0.f};
    for (int f = 0; f < F_; ++f) {
        float tv = tb[(size_t)f * E_];
        float4 pp = *(const float4*)&phT[f][0];
        h[0] += pp.x * tv; h[1] += pp.y * tv; h[2] += pp.z * tv; h[3] += pp.w * tv;
    }
#pragma unroll
    for (int p = 0; p < 4; ++p) h[p] = fabsf(h[p]);
    float* hrow = hm + (size_t)gv0 * E_ + e;
#pragma unroll
    for (int p = 0; p < 4; ++p) hrow[(size_t)p * E_] = h[p];
    atomicAdd(&ws[OFF_CSUM + b * E_ + e], h[0] + h[1] + h[2] + h[3]);
#pragma unroll
    for (int off = 32; off > 0; off >>= 1) {
#pragma unroll
        for (int p = 0; p < 4; ++p) h[p] += __shfl_down(h[p], off, 64);
    }
    int lane = tid & 63, wid = tid >> 6;
    if (lane == 0) {
#pragma unroll
        for (int p = 0; p < 4; ++p) red[wid][p] = h[p];
    }
    __syncthreads();
    if (tid < 4) {
        float d = red[0][tid] + red[1][tid] + red[2][tid] + red[3][tid];
        ws[OFF_RSD + gv0 + tid] = rsqrtf(d);
    }
}

// ---- tmp[b,e,c] = (1/csum[b,e]) * sum_v hm[b,v,e]*rsD[b,v]*x[b,v,c] ----
__global__ void k_tmp(const float* __restrict__ x, float* __restrict__ ws,
                      const float* __restrict__ hm) {
    int b = blockIdx.x >> 5;
    int e0 = (blockIdx.x & 31) * 8;
    int c = threadIdx.x;
    float acc[8] = {0.f, 0.f, 0.f, 0.f, 0.f, 0.f, 0.f, 0.f};
    const float* hb = hm + (size_t)b * V_ * E_ + e0;
    const float* xb = x + (size_t)b * V_ * C_ + c;
    const float* rb = &ws[OFF_RSD + b * V_];
    for (int v = 0; v < V_; ++v) {
        float xr = xb[(size_t)v * C_] * rb[v];
        float4 hA = *(const float4*)(hb + (size_t)v * E_);
        float4 hB = *(const float4*)(hb + (size_t)v * E_ + 4);
        acc[0] += hA.x * xr; acc[1] += hA.y * xr; acc[2] += hA.z * xr; acc[3] += hA.w * xr;
        acc[4] += hB.x * xr; acc[5] += hB.y * xr; acc[6] += hB.z * xr; acc[7] += hB.w * xr;
    }
#pragma unroll
    for (int j = 0; j < 8; ++j) {
        float binv = 1.0f / ws[OFF_CSUM + b * E_ + e0 + j];
        ws[OFF_TMP + ((size_t)b * E_ + e0 + j) * C_ + c] = acc[j] * binv;
    }
}

// ---- out = (x - rsD * (hm @ tmp)) @ W2 + b2 ; overwrites hm (d_out) in place ----
__global__ void k_out(const float* __restrict__ x, const float* __restrict__ w2,
                      const float* __restrict__ b2, const float* __restrict__ ws,
                      float* __restrict__ io) {
    __shared__ float hsT[E_][8];
    __shared__ float dT[C_][8];
    __shared__ float rsd_s[8];
    int gv0 = blockIdx.x * 8;
    int b = gv0 >> 12;
    int tid = threadIdx.x;
    const float* hmr = io + (size_t)gv0 * E_;
#pragma unroll
    for (int p = 0; p < 8; ++p) hsT[tid][p] = hmr[(size_t)p * E_ + tid];
    if (tid < 8) rsd_s[tid] = ws[OFF_RSD + gv0 + tid];
    __syncthreads();
    int c = tid;
    float agg[8] = {0.f, 0.f, 0.f, 0.f, 0.f, 0.f, 0.f, 0.f};
    const float* tb = &ws[OFF_TMP + (size_t)b * E_ * C_ + c];
    for (int e = 0; e < E_; ++e) {
        float tv = tb[(size_t)e * C_];
        float4 hA = *(const float4*)&hsT[e][0];
        float4 hB = *(const float4*)&hsT[e][4];
        agg[0] += hA.x * tv; agg[1] += hA.y * tv; agg[2] += hA.z * tv; agg[3] += hA.w * tv;
        agg[4] += hB.x * tv; agg[5] += hB.y * tv; agg[6] += hB.z * tv; agg[7] += hB.w * tv;
    }
    const float* xb = x + (size_t)gv0 * C_ + c;
#pragma unroll
    for (int p = 0; p < 8; ++p) dT[c][p] = xb[(size_t)p * C_] - rsd_s[p] * agg[p];
    __syncthreads();
    float o[8] = {0.f, 0.f, 0.f, 0.f, 0.f, 0.f, 0.f, 0.f};
    const float* wp = w2 + c;
    for (int cc = 0; cc < C_; ++cc) {
        float wv = wp[(size_t)cc * C_];
        float4 dA = *(const float4*)&dT[cc][0];
        float4 dB = *(const float4*)&dT[cc][4];
        o[0] += dA.x * wv; o[1] += dA.y * wv; o[2] += dA.z * wv; o[3] += dA.w * wv;
        o[4] += dB.x * wv; o[5] += dB.y * wv; o[6] += dB.z * wv; o[7] += dB.w * wv;
    }
    float bias = b2[c];
    __syncthreads();
    float* ob = io + (size_t)gv0 * C_ + c;
#pragma unroll
    for (int p = 0; p < 8; ++p) ob[(size_t)p * C_] = o[p] + bias;
}

extern "C" void kernel_launch(void* const* d_in, const int* in_sizes, int n_in,
                              void* d_out, int out_size, void* d_ws, size_t ws_size,
                              hipStream_t stream) {
    const float* x     = (const float*)d_in[0];
    const float* w_phi = (const float*)d_in[1];
    const float* b_phi = (const float*)d_in[2];
    const float* w_a   = (const float*)d_in[3];
    const float* b_a   = (const float*)d_in[4];
    const float* w_m   = (const float*)d_in[5];
    const float* b_m   = (const float*)d_in[6];
    const float* w2    = (const float*)d_in[7];
    const float* b2    = (const float*)d_in[8];
    float* ws = (float*)d_ws;
    float* io = (float*)d_out;

    bool big = ws_size >= WS_NEED_BYTES;

    if (big) {
        hipMemsetAsync(ws, 0, ZERO_SMALL * sizeof(float), stream);
        hipMemsetAsync(ws + OFF_XPT, 0, XPT_FLOATS * sizeof(float), stream);
        k_xsum<<<dim3(64), dim3(256), 0, stream>>>(x, ws);
        k_a<<<dim3(8), dim3(128), 0, stream>>>(w_a, b_a, ws);
        k_phi<<<dim3(4096), dim3(128), 0, stream>>>(x, w_phi, b_phi, ws, 1);
        k_padx<<<dim3(512), dim3(256), 0, stream>>>(x, ws);
        k_wmt<<<dim3(49), dim3(256), 0, stream>>>(w_m, ws);
        k_gemm1<<<dim3(392), dim3(512), 0, stream>>>(ws, (u16*)d_out);
        k_gemm2<<<dim3(64), dim3(256), 0, stream>>>((const u16*)d_out, ws);
    } else {
        // fallback: round-3 path (11.7 MB ws)
        hipMemsetAsync(ws, 0, ZERO_OLD * sizeof(float), stream);
        k_xsum<<<dim3(64), dim3(256), 0, stream>>>(x, ws);
        k_a<<<dim3(8), dim3(128), 0, stream>>>(w_a, b_a, ws);
        k_phi<<<dim3(4096), dim3(128), 0, stream>>>(x, w_phi, b_phi, ws, 0);
        k_g_old<<<dim3(3136), dim3(64), 0, stream>>>(x, w_m, ws);
    }
    k_tfix<<<dim3(1024), dim3(256), 0, stream>>>(b_m, ws);
    k_hd<<<dim3(8192), dim3(256), 0, stream>>>(ws, io);
    k_tmp<<<dim3(256), dim3(256), 0, stream>>>(x, ws, io);
    k_out<<<dim3(4096), dim3(256), 0, stream>>>(x, w2, b2, ws, io);
}

// Round 5
// 991.386 us; speedup vs baseline: 3.4654x; 1.3914x over previous
//
#include <hip/hip_runtime.h>
#include <hip/hip_bf16.h>

typedef unsigned short u16;
typedef unsigned int u32;
#define DI __device__ __forceinline__

typedef __attribute__((ext_vector_type(8))) short v8s;
typedef __attribute__((ext_vector_type(4))) float v4f;

constexpr int B_ = 8;
constexpr int V_ = 4096;   // 64*64
constexpr int C_ = 256;    // Cin = Cout
constexpr int F_ = 128;
constexpr int E_ = 256;
constexpr int KK_ = 49;    // 7x7
constexpr int PWS = 80;    // padded row stride (u16), mult of 8
constexpr int PS  = 5600;  // padded plane stride = 70*80 (u16), mult of 8

// ---- ws layout (float indices). Total 10,262,528 floats = 41.05 MB ----
constexpr size_t OFF_XSUM = 0;                       // 2048
constexpr size_t OFF_CSUM = 2048;                    // 2048
constexpr size_t OFF_SPHI = 4096;                    // 1024
constexpr size_t OFF_A    = 5120;                    // 1024
constexpr size_t OFF_T    = 6144;                    // tT[b][e][f] f32: 262144 (atomic)
constexpr size_t ZERO_HEAD = OFF_T + 262144;         // 268288: memset [0..here)
constexpr size_t OFF_RSD  = 268288;                  // 32768
constexpr size_t OFF_TMP  = 301056;                  // 524288 (atomic, zeroed)
constexpr size_t OFF_PHIT = 825344;                  // bf16 phiT[b][f][v]: 2097152 floats
constexpr size_t OFF_XPT  = 2922496;                 // bf16 xpadT[b][c][5600]: 5734400 floats
constexpr size_t XPT_FLOATS = 5734400;
constexpr size_t OFF_WMT  = 8656896;                 // bf16 wmT[kk][e][c]: 1605632 floats

DI float bf2f(u16 u) {
    union { u32 i; float f; } v; v.i = ((u32)u) << 16; return v.f;
}
DI u16 f2bf(float f) {
    union { float f; u32 i; } v; v.f = f;
    u32 r = v.i + 0x7fff + ((v.i >> 16) & 1);
    return (u16)(r >> 16);
}

// ---- xsum[b][c] = sum_v x[b,v,c] ----
__global__ void k_xsum(const float* __restrict__ x, float* __restrict__ ws) {
    int b = blockIdx.x >> 3;
    int chunk = blockIdx.x & 7;
    int c = threadIdx.x;
    const float* xb = x + ((size_t)b * V_ + chunk * 512) * C_ + c;
    float s = 0.f;
    for (int v = 0; v < 512; ++v) s += xb[(size_t)v * C_];
    atomicAdd(&ws[OFF_XSUM + b * C_ + c], s);
}

// ---- a[b][f] = mean(x) @ w_a + b_a ----
__global__ void k_a(const float* __restrict__ w_a, const float* __restrict__ b_a,
                    float* __restrict__ ws) {
    int b = blockIdx.x, f = threadIdx.x;
    float acc = b_a[f];
    const float* xs = &ws[OFF_XSUM + b * C_];
    for (int c = 0; c < C_; ++c)
        acc += (xs[c] * (1.0f / 4096.0f)) * w_a[c * F_ + f];
    ws[OFF_A + b * F_ + f] = acc;
}

// ---- phiT[b][f][v] = bf16(x @ w_phi + b_phi), sphi[b,f] = sum_v phi ----
__global__ void k_phi(const float* __restrict__ x, const float* __restrict__ w_phi,
                      const float* __restrict__ b_phi, float* __restrict__ ws) {
    __shared__ float xsT[C_][8];
    int r0 = blockIdx.x * 8;
    int b = r0 >> 12;
    int v0 = r0 & 4095;
    int tid = threadIdx.x;
    const float* xb = x + (size_t)r0 * C_;
    for (int i = tid; i < 8 * C_; i += 128) xsT[i & 255][i >> 8] = xb[i];
    __syncthreads();
    int f = tid;
    float bp = b_phi[f];
    float acc[8];
#pragma unroll
    for (int r = 0; r < 8; ++r) acc[r] = bp;
    const float* wp = w_phi + f;
    for (int c = 0; c < C_; ++c) {
        float w = wp[c * F_];
        float4 xa = *(const float4*)&xsT[c][0];
        float4 xb4 = *(const float4*)&xsT[c][4];
        acc[0] += xa.x * w;  acc[1] += xa.y * w;  acc[2] += xa.z * w;  acc[3] += xa.w * w;
        acc[4] += xb4.x * w; acc[5] += xb4.y * w; acc[6] += xb4.z * w; acc[7] += xb4.w * w;
    }
    u16 pb[8];
    float ssum = 0.f;
#pragma unroll
    for (int r = 0; r < 8; ++r) { pb[r] = f2bf(acc[r]); ssum += acc[r]; }
    u16* phiT = (u16*)&ws[OFF_PHIT];
    uint4 q;
    q.x = (u32)pb[0] | ((u32)pb[1] << 16);
    q.y = (u32)pb[2] | ((u32)pb[3] << 16);
    q.z = (u32)pb[4] | ((u32)pb[5] << 16);
    q.w = (u32)pb[6] | ((u32)pb[7] << 16);
    *(uint4*)(phiT + ((size_t)(b * F_ + f)) * V_ + v0) = q;
    atomicAdd(&ws[OFF_SPHI + b * F_ + f], ssum);
}

// ---- xpadT[b][c][(h+3)*80 + (w+3)] = bf16(x[b,h,w,c]), halo pre-zeroed ----
__global__ void k_padx(const float* __restrict__ x, float* __restrict__ ws) {
    __shared__ float tile[64][68];
    int b = blockIdx.x >> 6;
    int h = blockIdx.x & 63;
    int tid = threadIdx.x;
    u16* xpt = (u16*)&ws[OFF_XPT];
    for (int cc = 0; cc < 4; ++cc) {
        int c0 = cc * 64;
        int w = tid >> 2, q = tid & 3;
        const float* xr = x + ((size_t)(b * V_ + h * 64 + w)) * C_ + c0 + q * 16;
        float4 f0 = *(const float4*)(xr);
        float4 f1 = *(const float4*)(xr + 4);
        float4 f2 = *(const float4*)(xr + 8);
        float4 f3 = *(const float4*)(xr + 12);
        __syncthreads();
        *(float4*)&tile[w][q * 16]      = f0;
        *(float4*)&tile[w][q * 16 + 4]  = f1;
        *(float4*)&tile[w][q * 16 + 8]  = f2;
        *(float4*)&tile[w][q * 16 + 12] = f3;
        __syncthreads();
        int c = tid >> 2, j4 = tid & 3;
        u16* dst = xpt + ((size_t)(b * C_ + c0 + c)) * PS + (h + 3) * PWS + 3 + j4 * 16;
#pragma unroll
        for (int ww = 0; ww < 16; ++ww) dst[ww] = f2bf(tile[j4 * 16 + ww][c]);
    }
}

// ---- wmT[kk][e][c] = bf16(w_m[kk][c][e]) ----
__global__ void k_wmt(const float* __restrict__ w_m, float* __restrict__ ws) {
    int kk = blockIdx.x;
    int e = threadIdx.x;
    u16* wmt = (u16*)&ws[OFF_WMT];
    for (int c0 = 0; c0 < C_; c0 += 8) {
        u16 pk[8];
#pragma unroll
        for (int i = 0; i < 8; ++i)
            pk[i] = f2bf(w_m[((size_t)kk * C_ + c0 + i) * E_ + e]);
        uint4 q;
        q.x = (u32)pk[0] | ((u32)pk[1] << 16);
        q.y = (u32)pk[2] | ((u32)pk[3] << 16);
        q.z = (u32)pk[4] | ((u32)pk[5] << 16);
        q.w = (u32)pk[6] | ((u32)pk[7] << 16);
        *(uint4*)(wmt + ((size_t)(kk * E_ + e)) * C_ + c0) = q;
    }
}

// ---- gemm1 inner loop, templated on the static shift KX ----
template <int KX>
DI void g1_loop(const u16* __restrict__ phiT_b, const u16* __restrict__ xpt_b,
                int ky, u16* lds_a, u16* lds_b, int tid, v4f acc[4][4]) {
    int wave = tid >> 6, lane = tid & 63, quad = lane >> 4, l15 = lane & 15;
    int mi2 = wave >> 2, ni2 = wave & 3;
    int fA = tid >> 2, vsA = (tid & 3) * 8;
    int cB = tid >> 1, sB = (tid & 1) * 16;
    const u16* bbase = xpt_b + (size_t)cB * PS + (size_t)ky * PWS + sB;
    constexpr int J0 = KX >> 1;
#pragma unroll 1
    for (int chunk = 0; chunk < 128; ++chunk) {
        int v0 = chunk * 32;
        int h = chunk >> 1, w0 = (chunk & 1) * 32;
        uint4 a4 = *(const uint4*)(phiT_b + (size_t)fA * V_ + v0 + vsA);
        const u16* bp = bbase + h * PWS + w0;
        uint4 q0 = *(const uint4*)(bp);
        uint4 q1 = *(const uint4*)(bp + 8);
        u32 dw[12];
        dw[0] = q0.x; dw[1] = q0.y; dw[2] = q0.z; dw[3] = q0.w;
        dw[4] = q1.x; dw[5] = q1.y; dw[6] = q1.z; dw[7] = q1.w;
        if constexpr (KX >= 1) {
            uint4 q2 = *(const uint4*)(bp + 16);
            dw[8] = q2.x; dw[9] = q2.y; dw[10] = q2.z; dw[11] = q2.w;
        } else {
            dw[8] = dw[9] = dw[10] = dw[11] = 0;
        }
        u32 o[8];
        if constexpr ((KX & 1) == 0) {
#pragma unroll
            for (int i = 0; i < 8; ++i) o[i] = dw[J0 + i];
        } else {
#pragma unroll
            for (int i = 0; i < 8; ++i) o[i] = (dw[J0 + i] >> 16) | (dw[J0 + i + 1] << 16);
        }
        __syncthreads();
        *(uint4*)&lds_a[fA * 40 + vsA] = a4;
        *(uint4*)&lds_b[cB * 40 + sB]     = (uint4){o[0], o[1], o[2], o[3]};
        *(uint4*)&lds_b[cB * 40 + sB + 8] = (uint4){o[4], o[5], o[6], o[7]};
        __syncthreads();
        v8s afr[4], bfr[4];
#pragma unroll
        for (int ai = 0; ai < 4; ++ai)
            afr[ai] = *(const v8s*)&lds_a[(mi2 * 64 + ai * 16 + l15) * 40 + quad * 8];
#pragma unroll
        for (int bi = 0; bi < 4; ++bi)
            bfr[bi] = *(const v8s*)&lds_b[(ni2 * 64 + bi * 16 + l15) * 40 + quad * 8];
#pragma unroll
        for (int ai = 0; ai < 4; ++ai)
#pragma unroll
            for (int bi = 0; bi < 4; ++bi)
                acc[ai][bi] = __builtin_amdgcn_mfma_f32_16x16x32_bf16(
                    afr[ai], bfr[bi], acc[ai][bi], 0, 0, 0);
    }
}

// ---- MFMA: G[b,kk][f][c] = sum_v phi[v,f] * xpad[v+off,c]  (bf16 out) ----
__global__ __launch_bounds__(512, 4) void k_gemm1(const float* __restrict__ ws_c,
                                                  u16* __restrict__ G) {
    __shared__ u16 lds_a[F_ * 40];   // 10 KB
    __shared__ u16 lds_b[C_ * 40];   // 20 KB
    int b = blockIdx.x / KK_;
    int kk = blockIdx.x % KK_;
    int ky = kk / 7, kx = kk % 7;
    int tid = threadIdx.x;
    int wave = tid >> 6, lane = tid & 63, quad = lane >> 4, l15 = lane & 15;
    int mi2 = wave >> 2, ni2 = wave & 3;

    const u16* phiT_b = (const u16*)&ws_c[OFF_PHIT] + (size_t)b * F_ * V_;
    const u16* xpt_b  = (const u16*)&ws_c[OFF_XPT] + (size_t)b * C_ * PS;

    v4f acc[4][4];
#pragma unroll
    for (int i = 0; i < 4; ++i)
#pragma unroll
        for (int j = 0; j < 4; ++j) acc[i][j] = (v4f){0.f, 0.f, 0.f, 0.f};

    switch (kx) {
        case 0: g1_loop<0>(phiT_b, xpt_b, ky, lds_a, lds_b, tid, acc); break;
        case 1: g1_loop<1>(phiT_b, xpt_b, ky, lds_a, lds_b, tid, acc); break;
        case 2: g1_loop<2>(phiT_b, xpt_b, ky, lds_a, lds_b, tid, acc); break;
        case 3: g1_loop<3>(phiT_b, xpt_b, ky, lds_a, lds_b, tid, acc); break;
        case 4: g1_loop<4>(phiT_b, xpt_b, ky, lds_a, lds_b, tid, acc); break;
        case 5: g1_loop<5>(phiT_b, xpt_b, ky, lds_a, lds_b, tid, acc); break;
        case 6: g1_loop<6>(phiT_b, xpt_b, ky, lds_a, lds_b, tid, acc); break;
    }

    u16* Gb = G + ((size_t)(b * KK_ + kk)) * F_ * C_;
#pragma unroll
    for (int ai = 0; ai < 4; ++ai) {
#pragma unroll
        for (int bi = 0; bi < 4; ++bi) {
            int c = ni2 * 64 + bi * 16 + l15;
#pragma unroll
            for (int r = 0; r < 4; ++r) {
                int f = mi2 * 64 + ai * 16 + quad * 4 + r;
                Gb[(size_t)f * C_ + c] = f2bf(acc[ai][bi][r]);
            }
        }
    }
}

// ---- MFMA: tT[b][e][f] += sum_{kk in group, c} G[b,kk][f][c] * wmT[kk][e][c] ----
__global__ void k_gemm2(const u16* __restrict__ G, float* __restrict__ ws) {
    int blk = blockIdx.x;               // 448 = 8b * 2fi * 4ei * 7kg
    int kg = blk % 7; blk /= 7;
    int ei = blk % 4; blk /= 4;
    int fi = blk % 2; int b = blk / 2;
    int tid = threadIdx.x;
    int wave = tid >> 6, lane = tid & 63, quad = lane >> 4, l15 = lane & 15;
    int fbase = fi * 64 + wave * 16;
    int ebase = ei * 64;
    const u16* wmt = (const u16*)&ws[OFF_WMT];
    const u16* Gb = G + (size_t)b * KK_ * F_ * C_;
    v4f acc[4];
#pragma unroll
    for (int i = 0; i < 4; ++i) acc[i] = (v4f){0.f, 0.f, 0.f, 0.f};
    for (int kk = kg * 7; kk < kg * 7 + 7; ++kk) {
        const u16* Ga = Gb + ((size_t)kk * F_ + fbase + l15) * C_;
        const u16* Wb = wmt + ((size_t)kk * E_ + ebase + l15) * C_;
#pragma unroll 2
        for (int cs = 0; cs < 8; ++cs) {
            v8s af = *(const v8s*)(Ga + cs * 32 + quad * 8);
#pragma unroll
            for (int nt = 0; nt < 4; ++nt) {
                v8s bf = *(const v8s*)(Wb + (size_t)nt * 16 * C_ + cs * 32 + quad * 8);
                acc[nt] = __builtin_amdgcn_mfma_f32_16x16x32_bf16(af, bf, acc[nt], 0, 0, 0);
            }
        }
    }
#pragma unroll
    for (int nt = 0; nt < 4; ++nt)
#pragma unroll
        for (int r = 0; r < 4; ++r) {
            int e = ebase + nt * 16 + l15;
            int f = fbase + quad * 4 + r;
            atomicAdd(&ws[OFF_T + ((size_t)(b * E_ + e)) * F_ + f], acc[nt][r]);
        }
}

// ---- tT = a[b,f] * (tT + sphi[b,f]*b_m[e]) ----
__global__ void k_tfix(const float* __restrict__ b_m, float* __restrict__ ws) {
    int b = blockIdx.x >> 8, e = blockIdx.x & 255, f = threadIdx.x;
    float av = ws[OFF_A + b * F_ + f];
    float sp = ws[OFF_SPHI + b * F_ + f];
    size_t idx = OFF_T + ((size_t)(b * E_ + e)) * F_ + f;
    ws[idx] = av * (ws[idx] + sp * b_m[e]);
}

// ---- Hmat = |phi @ t| (f32 -> hm in d_out), rsD, csum ----
__global__ void k_hd(float* __restrict__ ws, float* __restrict__ hm) {
    __shared__ float phT[F_][4];
    __shared__ float red[4][4];
    int gv0 = blockIdx.x * 4;
    int b = gv0 >> 12;
    int v0g = gv0 & 4095;
    int tid = threadIdx.x;
    const u16* phiT = (const u16*)&ws[OFF_PHIT];
    for (int i = tid; i < 4 * F_; i += 256) {
        int f = i >> 2, p = i & 3;
        phT[f][p] = bf2f(phiT[((size_t)(b * F_ + f)) * V_ + v0g + p]);
    }
    __syncthreads();
    int e = tid;
    const float* tb = &ws[OFF_T + ((size_t)(b * E_ + e)) * F_];
    float h[4] = {0.f, 0.f, 0.f, 0.f};
    for (int f = 0; f < F_; f += 4) {
        float4 tv = *(const float4*)(tb + f);
        float tq[4] = {tv.x, tv.y, tv.z, tv.w};
#pragma unroll
        for (int q = 0; q < 4; ++q) {
            float4 pp = *(const float4*)&phT[f + q][0];
            h[0] += pp.x * tq[q]; h[1] += pp.y * tq[q];
            h[2] += pp.z * tq[q]; h[3] += pp.w * tq[q];
        }
    }
#pragma unroll
    for (int p = 0; p < 4; ++p) h[p] = fabsf(h[p]);
    float* hrow = hm + (size_t)gv0 * E_ + e;
#pragma unroll
    for (int p = 0; p < 4; ++p) hrow[(size_t)p * E_] = h[p];
    atomicAdd(&ws[OFF_CSUM + b * E_ + e], h[0] + h[1] + h[2] + h[3]);
#pragma unroll
    for (int off = 32; off > 0; off >>= 1) {
#pragma unroll
        for (int p = 0; p < 4; ++p) h[p] += __shfl_down(h[p], off, 64);
    }
    int lane = tid & 63, wid = tid >> 6;
    if (lane == 0) {
#pragma unroll
        for (int p = 0; p < 4; ++p) red[wid][p] = h[p];
    }
    __syncthreads();
    if (tid < 4) {
        float d = red[0][tid] + red[1][tid] + red[2][tid] + red[3][tid];
        ws[OFF_RSD + gv0 + tid] = rsqrtf(d);
    }
}

// ---- tmp[b,e,c] += sum_{v in chunk} hm[b,v,e]*rsD[b,v]*x[b,v,c]  (atomic) ----
__global__ void k_tmp(const float* __restrict__ x, float* __restrict__ ws,
                      const float* __restrict__ hm) {
    int blk = blockIdx.x;
    int vc = blk & 3; blk >>= 2;
    int eg = blk & 31; int b = blk >> 5;
    int e0 = eg * 8;
    int c = threadIdx.x;
    int v0 = vc * 1024;
    float acc[8] = {0.f, 0.f, 0.f, 0.f, 0.f, 0.f, 0.f, 0.f};
    const float* hb = hm + ((size_t)b * V_ + v0) * E_ + e0;
    const float* xb = x + ((size_t)b * V_ + v0) * C_ + c;
    const float* rb = &ws[OFF_RSD + b * V_ + v0];
    for (int v = 0; v < 1024; ++v) {
        float xr = xb[(size_t)v * C_] * rb[v];
        float4 hA = *(const float4*)(hb + (size_t)v * E_);
        float4 hB = *(const float4*)(hb + (size_t)v * E_ + 4);
        acc[0] += hA.x * xr; acc[1] += hA.y * xr; acc[2] += hA.z * xr; acc[3] += hA.w * xr;
        acc[4] += hB.x * xr; acc[5] += hB.y * xr; acc[6] += hB.z * xr; acc[7] += hB.w * xr;
    }
#pragma unroll
    for (int j = 0; j < 8; ++j)
        atomicAdd(&ws[OFF_TMP + ((size_t)b * E_ + e0 + j) * C_ + c], acc[j]);
}

// ---- out = (x - rsD * (hm @ (binv*tmp))) @ W2 + b2 ; overwrites hm in place ----
__global__ void k_out(const float* __restrict__ x, const float* __restrict__ w2,
                      const float* __restrict__ b2, const float* __restrict__ ws,
                      float* __restrict__ io) {
    __shared__ float hsT[E_][9];
    __shared__ float dT[C_][9];
    __shared__ float rsd_s[8];
    int gv0 = blockIdx.x * 8;
    int b = gv0 >> 12;
    int tid = threadIdx.x;
    const float* hmr = io + (size_t)gv0 * E_;
    float binv = 1.0f / ws[OFF_CSUM + b * E_ + tid];
#pragma unroll
    for (int p = 0; p < 8; ++p) hsT[tid][p] = hmr[(size_t)p * E_ + tid] * binv;
    if (tid < 8) rsd_s[tid] = ws[OFF_RSD + gv0 + tid];
    __syncthreads();
    int c = tid;
    float agg[8] = {0.f, 0.f, 0.f, 0.f, 0.f, 0.f, 0.f, 0.f};
    const float* tb = &ws[OFF_TMP + (size_t)b * E_ * C_ + c];
    for (int e = 0; e < E_; ++e) {
        float tv = tb[(size_t)e * C_];
        float4 hA = *(const float4*)&hsT[e][0];
        float4 hB = *(const float4*)&hsT[e][4];
        agg[0] += hA.x * tv; agg[1] += hA.y * tv; agg[2] += hA.z * tv; agg[3] += hA.w * tv;
        agg[4] += hB.x * tv; agg[5] += hB.y * tv; agg[6] += hB.z * tv; agg[7] += hB.w * tv;
    }
    const float* xb = x + (size_t)gv0 * C_ + c;
#pragma unroll
    for (int p = 0; p < 8; ++p) dT[c][p] = xb[(size_t)p * C_] - rsd_s[p] * agg[p];
    __syncthreads();
    float o[8] = {0.f, 0.f, 0.f, 0.f, 0.f, 0.f, 0.f, 0.f};
    const float* wp = w2 + c;
    for (int cc = 0; cc < C_; ++cc) {
        float wv = wp[(size_t)cc * C_];
        float4 dA = *(const float4*)&dT[cc][0];
        float4 dB = *(const float4*)&dT[cc][4];
        o[0] += dA.x * wv; o[1] += dA.y * wv; o[2] += dA.z * wv; o[3] += dA.w * wv;
        o[4] += dB.x * wv; o[5] += dB.y * wv; o[6] += dB.z * wv; o[7] += dB.w * wv;
    }
    float bias = b2[c];
    __syncthreads();
    float* ob = io + (size_t)gv0 * C_ + c;
#pragma unroll
    for (int p = 0; p < 8; ++p) ob[(size_t)p * C_] = o[p] + bias;
}

extern "C" void kernel_launch(void* const* d_in, const int* in_sizes, int n_in,
                              void* d_out, int out_size, void* d_ws, size_t ws_size,
                              hipStream_t stream) {
    const float* x     = (const float*)d_in[0];
    const float* w_phi = (const float*)d_in[1];
    const float* b_phi = (const float*)d_in[2];
    const float* w_a   = (const float*)d_in[3];
    const float* b_a   = (const float*)d_in[4];
    const float* w_m   = (const float*)d_in[5];
    const float* b_m   = (const float*)d_in[6];
    const float* w2    = (const float*)d_in[7];
    const float* b2    = (const float*)d_in[8];
    float* ws = (float*)d_ws;
    float* io = (float*)d_out;

    hipMemsetAsync(ws, 0, ZERO_HEAD * sizeof(float), stream);
    hipMemsetAsync(ws + OFF_TMP, 0, 524288 * sizeof(float), stream);
    hipMemsetAsync(ws + OFF_XPT, 0, XPT_FLOATS * sizeof(float), stream);
    k_xsum<<<dim3(64), dim3(256), 0, stream>>>(x, ws);
    k_a<<<dim3(8), dim3(128), 0, stream>>>(w_a, b_a, ws);
    k_phi<<<dim3(4096), dim3(128), 0, stream>>>(x, w_phi, b_phi, ws);
    k_padx<<<dim3(512), dim3(256), 0, stream>>>(x, ws);
    k_wmt<<<dim3(49), dim3(256), 0, stream>>>(w_m, ws);
    k_gemm1<<<dim3(392), dim3(512), 0, stream>>>(ws, (u16*)d_out);
    k_gemm2<<<dim3(448), dim3(256), 0, stream>>>((const u16*)d_out, ws);
    k_tfix<<<dim3(2048), dim3(128), 0, stream>>>(b_m, ws);
    k_hd<<<dim3(8192), dim3(256), 0, stream>>>(ws, io);
    k_tmp<<<dim3(1024), dim3(256), 0, stream>>>(x, ws, io);
    k_out<<<dim3(4096), dim3(256), 0, stream>>>(x, w2, b2, ws, io);
}

// Round 6
// 800.602 us; speedup vs baseline: 4.2912x; 1.2383x over previous
//
#include <hip/hip_runtime.h>
#include <hip/hip_bf16.h>

typedef unsigned short u16;
typedef unsigned int u32;
#define DI __device__ __forceinline__

typedef __attribute__((ext_vector_type(8))) short v8s;
typedef __attribute__((ext_vector_type(4))) float v4f;

constexpr int B_ = 8;
constexpr int V_ = 4096;   // 64*64
constexpr int C_ = 256;    // Cin = Cout
constexpr int F_ = 128;
constexpr int E_ = 256;
constexpr int KK_ = 49;    // 7x7
constexpr int PWS = 80;    // padded row stride (u16)
constexpr int PS  = 5600;  // padded plane stride (u16)

// ---- ws layout (float indices). Total 10,655,744 fl = 42.6 MB ----
constexpr size_t OFF_XSUM   = 0;         // 2048
constexpr size_t OFF_CSUM   = 2048;      // 2048
constexpr size_t OFF_SPHI   = 4096;      // 1024
constexpr size_t OFF_A      = 5120;      // 1024
constexpr size_t OFF_T      = 6144;      // f32 tT[b][e][f]: 262144 (atomic)
constexpr size_t OFF_TMPT   = 268288;    // f32 tmpT[b][c][e]: 524288 (atomic)
constexpr size_t ZERO_HEAD  = 792576;    // memset [0, here)
constexpr size_t OFF_TT16   = 792576;    // bf16 tT16[b][e][f]: 131072 fl
constexpr size_t OFF_T2T16  = 923648;    // bf16 tmp2T[b][c][e]: 262144 fl
constexpr size_t OFF_W2T16  = 1185792;   // bf16 w2T[co][c]: 32768 fl
constexpr size_t OFF_PHIT   = 1218560;   // bf16 phiT[b][f][v]: 2097152 fl
constexpr size_t OFF_XPT    = 3315712;   // bf16 xpadT: 5734400 fl; hmS16 overlays after gemm1
constexpr size_t XPT_FLOATS = 5734400;
constexpr size_t OFF_WMT    = 9050112;   // bf16 wmT[kk][e][c]: 1605632 fl

DI float bf2f(u16 u) {
    union { u32 i; float f; } v; v.i = ((u32)u) << 16; return v.f;
}
DI u16 f2bf(float f) {
    union { float f; u32 i; } v; v.f = f;
    u32 r = v.i + 0x7fff + ((v.i >> 16) & 1);
    return (u16)(r >> 16);
}

// ---- xsum[b][c] = sum_v x[b,v,c] ----
__global__ void k_xsum(const float* __restrict__ x, float* __restrict__ ws) {
    int b = blockIdx.x >> 3;
    int chunk = blockIdx.x & 7;
    int c = threadIdx.x;
    const float* xb = x + ((size_t)b * V_ + chunk * 512) * C_ + c;
    float s = 0.f;
    for (int v = 0; v < 512; ++v) s += xb[(size_t)v * C_];
    atomicAdd(&ws[OFF_XSUM + b * C_ + c], s);
}

// ---- a[b][f] = mean(x) @ w_a + b_a ----
__global__ void k_a(const float* __restrict__ w_a, const float* __restrict__ b_a,
                    float* __restrict__ ws) {
    int b = blockIdx.x, f = threadIdx.x;
    float acc = b_a[f];
    const float* xs = &ws[OFF_XSUM + b * C_];
    for (int c = 0; c < C_; ++c)
        acc += (xs[c] * (1.0f / 4096.0f)) * w_a[c * F_ + f];
    ws[OFF_A + b * F_ + f] = acc;
}

// ---- phiT[b][f][v] = bf16(x @ w_phi + b_phi), sphi ----
__global__ void k_phi(const float* __restrict__ x, const float* __restrict__ w_phi,
                      const float* __restrict__ b_phi, float* __restrict__ ws) {
    __shared__ float xsT[C_][8];
    int r0 = blockIdx.x * 8;
    int b = r0 >> 12;
    int v0 = r0 & 4095;
    int tid = threadIdx.x;
    const float* xb = x + (size_t)r0 * C_;
    for (int i = tid; i < 8 * C_; i += 128) xsT[i & 255][i >> 8] = xb[i];
    __syncthreads();
    int f = tid;
    float bp = b_phi[f];
    float acc[8];
#pragma unroll
    for (int r = 0; r < 8; ++r) acc[r] = bp;
    const float* wp = w_phi + f;
    for (int c = 0; c < C_; ++c) {
        float w = wp[c * F_];
        float4 xa = *(const float4*)&xsT[c][0];
        float4 xb4 = *(const float4*)&xsT[c][4];
        acc[0] += xa.x * w;  acc[1] += xa.y * w;  acc[2] += xa.z * w;  acc[3] += xa.w * w;
        acc[4] += xb4.x * w; acc[5] += xb4.y * w; acc[6] += xb4.z * w; acc[7] += xb4.w * w;
    }
    u16 pb[8];
    float ssum = 0.f;
#pragma unroll
    for (int r = 0; r < 8; ++r) { pb[r] = f2bf(acc[r]); ssum += acc[r]; }
    u16* phiT = (u16*)&ws[OFF_PHIT];
    uint4 q;
    q.x = (u32)pb[0] | ((u32)pb[1] << 16);
    q.y = (u32)pb[2] | ((u32)pb[3] << 16);
    q.z = (u32)pb[4] | ((u32)pb[5] << 16);
    q.w = (u32)pb[6] | ((u32)pb[7] << 16);
    *(uint4*)(phiT + ((size_t)(b * F_ + f)) * V_ + v0) = q;
    atomicAdd(&ws[OFF_SPHI + b * F_ + f], ssum);
}

// ---- xpadT[b][c][(h+3)*80 + (w+3)] = bf16(x), halo pre-zeroed ----
__global__ void k_padx(const float* __restrict__ x, float* __restrict__ ws) {
    __shared__ float tile[64][68];
    int b = blockIdx.x >> 6;
    int h = blockIdx.x & 63;
    int tid = threadIdx.x;
    u16* xpt = (u16*)&ws[OFF_XPT];
    for (int cc = 0; cc < 4; ++cc) {
        int c0 = cc * 64;
        int w = tid >> 2, q = tid & 3;
        const float* xr = x + ((size_t)(b * V_ + h * 64 + w)) * C_ + c0 + q * 16;
        float4 f0 = *(const float4*)(xr);
        float4 f1 = *(const float4*)(xr + 4);
        float4 f2 = *(const float4*)(xr + 8);
        float4 f3 = *(const float4*)(xr + 12);
        __syncthreads();
        *(float4*)&tile[w][q * 16]      = f0;
        *(float4*)&tile[w][q * 16 + 4]  = f1;
        *(float4*)&tile[w][q * 16 + 8]  = f2;
        *(float4*)&tile[w][q * 16 + 12] = f3;
        __syncthreads();
        int c = tid >> 2, j4 = tid & 3;
        u16* dst = xpt + ((size_t)(b * C_ + c0 + c)) * PS + (h + 3) * PWS + 3 + j4 * 16;
#pragma unroll
        for (int ww = 0; ww < 16; ++ww) dst[ww] = f2bf(tile[j4 * 16 + ww][c]);
    }
}

// ---- wmT[kk][e][c] = bf16(w_m[kk][c][e]) ----
__global__ void k_wmt(const float* __restrict__ w_m, float* __restrict__ ws) {
    int kk = blockIdx.x;
    int e = threadIdx.x;
    u16* wmt = (u16*)&ws[OFF_WMT];
    for (int c0 = 0; c0 < C_; c0 += 8) {
        u16 pk[8];
#pragma unroll
        for (int i = 0; i < 8; ++i)
            pk[i] = f2bf(w_m[((size_t)kk * C_ + c0 + i) * E_ + e]);
        uint4 q;
        q.x = (u32)pk[0] | ((u32)pk[1] << 16);
        q.y = (u32)pk[2] | ((u32)pk[3] << 16);
        q.z = (u32)pk[4] | ((u32)pk[5] << 16);
        q.w = (u32)pk[6] | ((u32)pk[7] << 16);
        *(uint4*)(wmt + ((size_t)(kk * E_ + e)) * C_ + c0) = q;
    }
}

// ---- w2T16[co][c] = bf16(w2[c][co]) ----
__global__ void k_w2t(const float* __restrict__ w2, float* __restrict__ ws) {
    int co = blockIdx.x, c = threadIdx.x;
    ((u16*)&ws[OFF_W2T16])[(size_t)co * C_ + c] = f2bf(w2[(size_t)c * C_ + co]);
}

// ---- gemm1 inner loop (static shift KX) ----
template <int KX>
DI void g1_loop(const u16* __restrict__ phiT_b, const u16* __restrict__ xpt_b,
                int ky, u16* lds_a, u16* lds_b, int tid, v4f acc[4][4]) {
    int wave = tid >> 6, lane = tid & 63, quad = lane >> 4, l15 = lane & 15;
    int mi2 = wave >> 2, ni2 = wave & 3;
    int fA = tid >> 2, vsA = (tid & 3) * 8;
    int cB = tid >> 1, sB = (tid & 1) * 16;
    const u16* bbase = xpt_b + (size_t)cB * PS + (size_t)ky * PWS + sB;
    constexpr int J0 = KX >> 1;
#pragma unroll 1
    for (int chunk = 0; chunk < 128; ++chunk) {
        int v0 = chunk * 32;
        int h = chunk >> 1, w0 = (chunk & 1) * 32;
        uint4 a4 = *(const uint4*)(phiT_b + (size_t)fA * V_ + v0 + vsA);
        const u16* bp = bbase + h * PWS + w0;
        uint4 q0 = *(const uint4*)(bp);
        uint4 q1 = *(const uint4*)(bp + 8);
        u32 dw[12];
        dw[0] = q0.x; dw[1] = q0.y; dw[2] = q0.z; dw[3] = q0.w;
        dw[4] = q1.x; dw[5] = q1.y; dw[6] = q1.z; dw[7] = q1.w;
        if constexpr (KX >= 1) {
            uint4 q2 = *(const uint4*)(bp + 16);
            dw[8] = q2.x; dw[9] = q2.y; dw[10] = q2.z; dw[11] = q2.w;
        } else {
            dw[8] = dw[9] = dw[10] = dw[11] = 0;
        }
        u32 o[8];
        if constexpr ((KX & 1) == 0) {
#pragma unroll
            for (int i = 0; i < 8; ++i) o[i] = dw[J0 + i];
        } else {
#pragma unroll
            for (int i = 0; i < 8; ++i) o[i] = (dw[J0 + i] >> 16) | (dw[J0 + i + 1] << 16);
        }
        __syncthreads();
        *(uint4*)&lds_a[fA * 40 + vsA] = a4;
        *(uint4*)&lds_b[cB * 40 + sB]     = (uint4){o[0], o[1], o[2], o[3]};
        *(uint4*)&lds_b[cB * 40 + sB + 8] = (uint4){o[4], o[5], o[6], o[7]};
        __syncthreads();
        v8s afr[4], bfr[4];
#pragma unroll
        for (int ai = 0; ai < 4; ++ai)
            afr[ai] = *(const v8s*)&lds_a[(mi2 * 64 + ai * 16 + l15) * 40 + quad * 8];
#pragma unroll
        for (int bi = 0; bi < 4; ++bi)
            bfr[bi] = *(const v8s*)&lds_b[(ni2 * 64 + bi * 16 + l15) * 40 + quad * 8];
#pragma unroll
        for (int ai = 0; ai < 4; ++ai)
#pragma unroll
            for (int bi = 0; bi < 4; ++bi)
                acc[ai][bi] = __builtin_amdgcn_mfma_f32_16x16x32_bf16(
                    afr[ai], bfr[bi], acc[ai][bi], 0, 0, 0);
    }
}

// ---- MFMA: G[b,kk][f][c] (bf16, in d_out) ----
__global__ __launch_bounds__(512, 4) void k_gemm1(const float* __restrict__ ws_c,
                                                  u16* __restrict__ G) {
    __shared__ u16 lds_a[F_ * 40];
    __shared__ u16 lds_b[C_ * 40];
    int b = blockIdx.x / KK_;
    int kk = blockIdx.x % KK_;
    int ky = kk / 7, kx = kk % 7;
    int tid = threadIdx.x;
    int wave = tid >> 6, lane = tid & 63, quad = lane >> 4, l15 = lane & 15;
    int mi2 = wave >> 2, ni2 = wave & 3;
    const u16* phiT_b = (const u16*)&ws_c[OFF_PHIT] + (size_t)b * F_ * V_;
    const u16* xpt_b  = (const u16*)&ws_c[OFF_XPT] + (size_t)b * C_ * PS;
    v4f acc[4][4];
#pragma unroll
    for (int i = 0; i < 4; ++i)
#pragma unroll
        for (int j = 0; j < 4; ++j) acc[i][j] = (v4f){0.f, 0.f, 0.f, 0.f};
    switch (kx) {
        case 0: g1_loop<0>(phiT_b, xpt_b, ky, lds_a, lds_b, tid, acc); break;
        case 1: g1_loop<1>(phiT_b, xpt_b, ky, lds_a, lds_b, tid, acc); break;
        case 2: g1_loop<2>(phiT_b, xpt_b, ky, lds_a, lds_b, tid, acc); break;
        case 3: g1_loop<3>(phiT_b, xpt_b, ky, lds_a, lds_b, tid, acc); break;
        case 4: g1_loop<4>(phiT_b, xpt_b, ky, lds_a, lds_b, tid, acc); break;
        case 5: g1_loop<5>(phiT_b, xpt_b, ky, lds_a, lds_b, tid, acc); break;
        case 6: g1_loop<6>(phiT_b, xpt_b, ky, lds_a, lds_b, tid, acc); break;
    }
    u16* Gb = G + ((size_t)(b * KK_ + kk)) * F_ * C_;
#pragma unroll
    for (int ai = 0; ai < 4; ++ai)
#pragma unroll
        for (int bi = 0; bi < 4; ++bi) {
            int c = ni2 * 64 + bi * 16 + l15;
#pragma unroll
            for (int r = 0; r < 4; ++r) {
                int f = mi2 * 64 + ai * 16 + quad * 4 + r;
                Gb[(size_t)f * C_ + c] = f2bf(acc[ai][bi][r]);
            }
        }
}

// ---- MFMA: tT[b][e][f] += G @ wmT (atomic f32) ----
__global__ void k_gemm2(const u16* __restrict__ G, float* __restrict__ ws) {
    int blk = blockIdx.x;
    int kg = blk % 7; blk /= 7;
    int ei = blk % 4; blk /= 4;
    int fi = blk % 2; int b = blk / 2;
    int tid = threadIdx.x;
    int wave = tid >> 6, lane = tid & 63, quad = lane >> 4, l15 = lane & 15;
    int fbase = fi * 64 + wave * 16;
    int ebase = ei * 64;
    const u16* wmt = (const u16*)&ws[OFF_WMT];
    const u16* Gb = G + (size_t)b * KK_ * F_ * C_;
    v4f acc[4];
#pragma unroll
    for (int i = 0; i < 4; ++i) acc[i] = (v4f){0.f, 0.f, 0.f, 0.f};
    for (int kk = kg * 7; kk < kg * 7 + 7; ++kk) {
        const u16* Ga = Gb + ((size_t)kk * F_ + fbase + l15) * C_;
        const u16* Wb = wmt + ((size_t)kk * E_ + ebase + l15) * C_;
#pragma unroll 2
        for (int cs = 0; cs < 8; ++cs) {
            v8s af = *(const v8s*)(Ga + cs * 32 + quad * 8);
#pragma unroll
            for (int nt = 0; nt < 4; ++nt) {
                v8s bf = *(const v8s*)(Wb + (size_t)nt * 16 * C_ + cs * 32 + quad * 8);
                acc[nt] = __builtin_amdgcn_mfma_f32_16x16x32_bf16(af, bf, acc[nt], 0, 0, 0);
            }
        }
    }
#pragma unroll
    for (int nt = 0; nt < 4; ++nt)
#pragma unroll
        for (int r = 0; r < 4; ++r) {
            int e = ebase + nt * 16 + l15;
            int f = fbase + quad * 4 + r;
            atomicAdd(&ws[OFF_T + ((size_t)(b * E_ + e)) * F_ + f], acc[nt][r]);
        }
}

// ---- tT16[b][e][f] = bf16( a[b,f] * (tT + sphi[b,f]*b_m[e]) ) ----
__global__ void k_tfix(const float* __restrict__ b_m, float* __restrict__ ws) {
    int b = blockIdx.x >> 8, e = blockIdx.x & 255, f = threadIdx.x;
    float av = ws[OFF_A + b * F_ + f];
    float sp = ws[OFF_SPHI + b * F_ + f];
    float t = av * (ws[OFF_T + ((size_t)(b * E_ + e)) * F_ + f] + sp * b_m[e]);
    ((u16*)&ws[OFF_TT16])[((size_t)(b * E_ + e)) * F_ + f] = f2bf(t);
}

// ---- MFMA: hmS16[v][e] = bf16(rsD[v]*|phi@t|), csum atomic ----
__global__ void k_hd(float* __restrict__ ws) {
    __shared__ u16 phiL[64 * 136];
    int b = blockIdx.x >> 6;
    int v0 = (blockIdx.x & 63) * 64;
    int tid = threadIdx.x;
    // stage phi[v][f] from phiT[f][v]
    {
        int f = tid & 127, seg = (tid >> 7) * 32;
        const u16* src = (const u16*)&ws[OFF_PHIT] + ((size_t)(b * F_ + f)) * V_ + v0 + seg;
        uint4 q0 = *(const uint4*)(src);
        uint4 q1 = *(const uint4*)(src + 8);
        uint4 q2 = *(const uint4*)(src + 16);
        uint4 q3 = *(const uint4*)(src + 24);
        u32 dw[16] = {q0.x, q0.y, q0.z, q0.w, q1.x, q1.y, q1.z, q1.w,
                      q2.x, q2.y, q2.z, q2.w, q3.x, q3.y, q3.z, q3.w};
#pragma unroll
        for (int j = 0; j < 16; ++j) {
            phiL[(seg + 2 * j) * 136 + f]     = (u16)(dw[j] & 0xffff);
            phiL[(seg + 2 * j + 1) * 136 + f] = (u16)(dw[j] >> 16);
        }
    }
    __syncthreads();
    int wave = tid >> 6, lane = tid & 63, quad = lane >> 4, l15 = lane & 15;
    const u16* tt = (const u16*)&ws[OFF_TT16] + (size_t)b * E_ * F_;
    v4f acc[16];
#pragma unroll
    for (int i = 0; i < 16; ++i) acc[i] = (v4f){0.f, 0.f, 0.f, 0.f};
#pragma unroll
    for (int kc = 0; kc < 4; ++kc) {
        v8s af = *(const v8s*)&phiL[(wave * 16 + l15) * 136 + kc * 32 + quad * 8];
#pragma unroll
        for (int nt = 0; nt < 16; ++nt) {
            v8s bf = *(const v8s*)(tt + (size_t)(nt * 16 + l15) * F_ + kc * 32 + quad * 8);
            acc[nt] = __builtin_amdgcn_mfma_f32_16x16x32_bf16(af, bf, acc[nt], 0, 0, 0);
        }
    }
#pragma unroll
    for (int nt = 0; nt < 16; ++nt)
#pragma unroll
        for (int r = 0; r < 4; ++r) acc[nt][r] = fabsf(acc[nt][r]);
    // row sums over e (256) -> rsD
    v4f rs = acc[0];
#pragma unroll
    for (int nt = 1; nt < 16; ++nt) rs += acc[nt];
#pragma unroll
    for (int m = 1; m < 16; m <<= 1) {
#pragma unroll
        for (int r = 0; r < 4; ++r) rs[r] += __shfl_xor(rs[r], m, 64);
    }
    float rsd[4];
#pragma unroll
    for (int r = 0; r < 4; ++r) rsd[r] = rsqrtf(rs[r]);
    // col sums (unscaled) -> csum atomics
#pragma unroll
    for (int nt = 0; nt < 16; ++nt) {
        float cs = acc[nt][0] + acc[nt][1] + acc[nt][2] + acc[nt][3];
        atomicAdd(&ws[OFF_CSUM + b * E_ + nt * 16 + l15], cs);
    }
    // store hmS16 = rsD*H
    u16* hm = (u16*)&ws[OFF_XPT];
#pragma unroll
    for (int nt = 0; nt < 16; ++nt)
#pragma unroll
        for (int r = 0; r < 4; ++r) {
            int v = v0 + wave * 16 + quad * 4 + r;
            hm[((size_t)(b * V_ + v)) * E_ + nt * 16 + l15] = f2bf(acc[nt][r] * rsd[r]);
        }
}

// ---- MFMA: tmpT[b][c][e] += sum_v xT[c][v]*hmS^T[e][v] (atomic f32) ----
__global__ __launch_bounds__(512, 2) void k_tmp(const float* __restrict__ x,
                                                float* __restrict__ ws) {
    __shared__ u16 xT[256 * 40];
    __shared__ u16 hT[128 * 40];
    int blk = blockIdx.x;
    int eh = blk & 1; blk >>= 1;
    int vs = blk & 15; int b = blk >> 4;
    int v0b = vs * 256;
    int tid = threadIdx.x;
    int wave = tid >> 6, lane = tid & 63, quad = lane >> 4, l15 = lane & 15;
    int m0 = wave * 32;
    const u16* hmS = (const u16*)&ws[OFF_XPT];
    v4f acc[2][8];
#pragma unroll
    for (int i = 0; i < 2; ++i)
#pragma unroll
        for (int j = 0; j < 8; ++j) acc[i][j] = (v4f){0.f, 0.f, 0.f, 0.f};
    int sv = tid & 31, sg = tid >> 5;   // staging roles
#pragma unroll 1
    for (int ch = 0; ch < 8; ++ch) {
        int vbase = v0b + ch * 32;
        // load x row (16 f32) and hm row (8 u16) into regs
        const float* xr = x + ((size_t)(b * V_ + vbase + sv)) * C_ + sg * 16;
        float4 xf0 = *(const float4*)(xr);
        float4 xf1 = *(const float4*)(xr + 4);
        float4 xf2 = *(const float4*)(xr + 8);
        float4 xf3 = *(const float4*)(xr + 12);
        const u16* hr = hmS + ((size_t)(b * V_ + vbase + sv)) * E_ + eh * 128 + sg * 8;
        uint4 hq = *(const uint4*)hr;
        u16 hp[8] = {(u16)(hq.x & 0xffff), (u16)(hq.x >> 16), (u16)(hq.y & 0xffff),
                     (u16)(hq.y >> 16), (u16)(hq.z & 0xffff), (u16)(hq.z >> 16),
                     (u16)(hq.w & 0xffff), (u16)(hq.w >> 16)};
        float xv[16] = {xf0.x, xf0.y, xf0.z, xf0.w, xf1.x, xf1.y, xf1.z, xf1.w,
                        xf2.x, xf2.y, xf2.z, xf2.w, xf3.x, xf3.y, xf3.z, xf3.w};
        __syncthreads();
#pragma unroll
        for (int i = 0; i < 16; ++i) xT[(sg * 16 + i) * 40 + sv] = f2bf(xv[i]);
#pragma unroll
        for (int i = 0; i < 8; ++i) hT[(sg * 8 + i) * 40 + sv] = hp[i];
        __syncthreads();
        v8s a0 = *(const v8s*)&xT[(m0 + l15) * 40 + quad * 8];
        v8s a1 = *(const v8s*)&xT[(m0 + 16 + l15) * 40 + quad * 8];
#pragma unroll
        for (int nt = 0; nt < 8; ++nt) {
            v8s bf = *(const v8s*)&hT[(nt * 16 + l15) * 40 + quad * 8];
            acc[0][nt] = __builtin_amdgcn_mfma_f32_16x16x32_bf16(a0, bf, acc[0][nt], 0, 0, 0);
            acc[1][nt] = __builtin_amdgcn_mfma_f32_16x16x32_bf16(a1, bf, acc[1][nt], 0, 0, 0);
        }
    }
#pragma unroll
    for (int mt = 0; mt < 2; ++mt)
#pragma unroll
        for (int nt = 0; nt < 8; ++nt)
#pragma unroll
            for (int r = 0; r < 4; ++r) {
                int c = m0 + mt * 16 + quad * 4 + r;
                int e = eh * 128 + nt * 16 + l15;
                atomicAdd(&ws[OFF_TMPT + ((size_t)(b * C_ + c)) * E_ + e], acc[mt][nt][r]);
            }
}

// ---- tmp2T16[c][e] = bf16(tmpT[c][e] / csum[e]) ----
__global__ void k_t2fix(float* __restrict__ ws) {
    int b = blockIdx.x >> 8, c = blockIdx.x & 255, e = threadIdx.x;
    float binv = 1.0f / ws[OFF_CSUM + b * E_ + e];
    float tv = ws[OFF_TMPT + ((size_t)(b * C_ + c)) * E_ + e];
    ((u16*)&ws[OFF_T2T16])[((size_t)(b * C_ + c)) * E_ + e] = f2bf(tv * binv);
}

// ---- MFMA fused: out = (x - hmS16 @ tmp2T16) @ W2 + b2 ----
__global__ __launch_bounds__(256, 2) void k_out(const float* __restrict__ x,
                                                const float* __restrict__ b2,
                                                const float* __restrict__ ws,
                                                float* __restrict__ io) {
    __shared__ u16 dL[64 * 264];
    int b = blockIdx.x >> 6;
    int v0 = (blockIdx.x & 63) * 64;
    int tid = threadIdx.x;
    int wave = tid >> 6, lane = tid & 63, quad = lane >> 4, l15 = lane & 15;
    const u16* hm = (const u16*)&ws[OFF_XPT] + ((size_t)(b * V_ + v0 + wave * 16 + l15)) * E_;
    const u16* t2 = (const u16*)&ws[OFF_T2T16] + (size_t)b * C_ * E_;
    v4f acc[16];
#pragma unroll
    for (int i = 0; i < 16; ++i) acc[i] = (v4f){0.f, 0.f, 0.f, 0.f};
#pragma unroll 2
    for (int kc = 0; kc < 8; ++kc) {
        v8s af = *(const v8s*)(hm + kc * 32 + quad * 8);
#pragma unroll
        for (int nt = 0; nt < 16; ++nt) {
            v8s bf = *(const v8s*)(t2 + (size_t)(nt * 16 + l15) * E_ + kc * 32 + quad * 8);
            acc[nt] = __builtin_amdgcn_mfma_f32_16x16x32_bf16(af, bf, acc[nt], 0, 0, 0);
        }
    }
#pragma unroll
    for (int nt = 0; nt < 16; ++nt)
#pragma unroll
        for (int r = 0; r < 4; ++r) {
            int v = wave * 16 + quad * 4 + r;
            int c = nt * 16 + l15;
            float xv = x[((size_t)(b * V_ + v0 + v)) * C_ + c];
            dL[v * 264 + c] = f2bf(xv - acc[nt][r]);
        }
    __syncthreads();
    const u16* w2t = (const u16*)&ws[OFF_W2T16];
    v4f acc2[16];
#pragma unroll
    for (int i = 0; i < 16; ++i) acc2[i] = (v4f){0.f, 0.f, 0.f, 0.f};
#pragma unroll 2
    for (int kc = 0; kc < 8; ++kc) {
        v8s af = *(const v8s*)&dL[(wave * 16 + l15) * 264 + kc * 32 + quad * 8];
#pragma unroll
        for (int nt = 0; nt < 16; ++nt) {
            v8s bf = *(const v8s*)(w2t + (size_t)(nt * 16 + l15) * C_ + kc * 32 + quad * 8);
            acc2[nt] = __builtin_amdgcn_mfma_f32_16x16x32_bf16(af, bf, acc2[nt], 0, 0, 0);
        }
    }
#pragma unroll
    for (int nt = 0; nt < 16; ++nt)
#pragma unroll
        for (int r = 0; r < 4; ++r) {
            int v = wave * 16 + quad * 4 + r;
            int co = nt * 16 + l15;
            io[((size_t)(b * V_ + v0 + v)) * C_ + co] = acc2[nt][r] + b2[co];
        }
}

extern "C" void kernel_launch(void* const* d_in, const int* in_sizes, int n_in,
                              void* d_out, int out_size, void* d_ws, size_t ws_size,
                              hipStream_t stream) {
    const float* x     = (const float*)d_in[0];
    const float* w_phi = (const float*)d_in[1];
    const float* b_phi = (const float*)d_in[2];
    const float* w_a   = (const float*)d_in[3];
    const float* b_a   = (const float*)d_in[4];
    const float* w_m   = (const float*)d_in[5];
    const float* b_m   = (const float*)d_in[6];
    const float* w2    = (const float*)d_in[7];
    const float* b2    = (const float*)d_in[8];
    float* ws = (float*)d_ws;
    float* io = (float*)d_out;

    hipMemsetAsync(ws, 0, ZERO_HEAD * sizeof(float), stream);
    hipMemsetAsync(ws + OFF_XPT, 0, XPT_FLOATS * sizeof(float), stream);
    k_xsum<<<dim3(64), dim3(256), 0, stream>>>(x, ws);
    k_a<<<dim3(8), dim3(128), 0, stream>>>(w_a, b_a, ws);
    k_phi<<<dim3(4096), dim3(128), 0, stream>>>(x, w_phi, b_phi, ws);
    k_padx<<<dim3(512), dim3(256), 0, stream>>>(x, ws);
    k_wmt<<<dim3(49), dim3(256), 0, stream>>>(w_m, ws);
    k_w2t<<<dim3(256), dim3(256), 0, stream>>>(w2, ws);
    k_gemm1<<<dim3(392), dim3(512), 0, stream>>>(ws, (u16*)d_out);
    k_gemm2<<<dim3(448), dim3(256), 0, stream>>>((const u16*)d_out, ws);
    k_tfix<<<dim3(2048), dim3(128), 0, stream>>>(b_m, ws);
    k_hd<<<dim3(512), dim3(256), 0, stream>>>(ws);
    k_tmp<<<dim3(256), dim3(512), 0, stream>>>(x, ws);
    k_t2fix<<<dim3(2048), dim3(256), 0, stream>>>(ws);
    k_out<<<dim3(512), dim3(256), 0, stream>>>(x, b2, ws, io);
}